// Round 6
// baseline (266.822 us; speedup 1.0000x reference)
//
#include <hip/hip_runtime.h>
#include <math.h>

#define NUM 576
#define BSTR 50
#define NTH 384
// dynamic LDS: band (576*50) + NTH-float dummy sink
#define CHOL_LDS_BYTES ((NUM * BSTR + NTH) * sizeof(float))

__device__ __forceinline__ float leakyf(float v) { return v > 0.f ? v : 0.01f * v; }
__device__ __forceinline__ float sigmoidf(float v) { return 1.f / (1.f + __expf(-v)); }
__device__ __forceinline__ float rdlane(float v, int l) {
  return __uint_as_float(__builtin_amdgcn_readlane(__float_as_uint(v), l));
}

// ---------------------------------------------------------------------------
// conv1: 3x3 pad1 conv on x (4,64,24,24) for BOTH branches, + leaky_relu.
// ---------------------------------------------------------------------------
__global__ __launch_bounds__(576) void conv1_kernel(
    const float* __restrict__ x,
    const float* __restrict__ wa, const float* __restrict__ ba,
    const float* __restrict__ wg, const float* __restrict__ bg,
    float* __restrict__ outa, float* __restrict__ outg)
{
  __shared__ float sx[16 * 576];
  const int co = blockIdx.x, n = blockIdx.y;
  const int tid = threadIdx.x;
  const int py = tid / 24, px = tid - py * 24;
  float acc_a = ba[co];
  float acc_g = bg[co];
  for (int c0 = 0; c0 < 64; c0 += 16) {
    __syncthreads();
#pragma unroll
    for (int k = 0; k < 16; ++k)
      sx[k * 576 + tid] = x[(n * 64 + c0 + k) * 576 + tid];
    __syncthreads();
#pragma unroll 4
    for (int k = 0; k < 16; ++k) {
      const float* wpa = wa + (co * 64 + c0 + k) * 9;
      const float* wpg = wg + (co * 64 + c0 + k) * 9;
#pragma unroll
      for (int dy = 0; dy < 3; ++dy) {
        const int yy = py + dy - 1;
        const bool oky = (unsigned)yy < 24u;
        const int iy = yy < 0 ? 0 : (yy > 23 ? 23 : yy);
#pragma unroll
        for (int dx = 0; dx < 3; ++dx) {
          const int xx = px + dx - 1;
          const bool ok = oky && ((unsigned)xx < 24u);
          const int ix = xx < 0 ? 0 : (xx > 23 ? 23 : xx);
          const float v = ok ? sx[k * 576 + iy * 24 + ix] : 0.f;
          acc_a += v * wpa[dy * 3 + dx];
          acc_g += v * wpg[dy * 3 + dx];
        }
      }
    }
  }
  const int o = (n * 64 + co) * 576 + tid;
  outa[o] = leakyf(acc_a);
  outg[o] = leakyf(acc_g);
}

// ---------------------------------------------------------------------------
// conv2: second 3x3 conv per branch. blockIdx.z selects branch.
// ---------------------------------------------------------------------------
__global__ __launch_bounds__(576) void conv2_kernel(
    const float* __restrict__ t1a, const float* __restrict__ t1g,
    const float* __restrict__ wa, const float* __restrict__ ba,
    const float* __restrict__ wg, const float* __restrict__ bg,
    float* __restrict__ att, float* __restrict__ grd)
{
  __shared__ float sx[16 * 576];
  const int co = blockIdx.x, n = blockIdx.y, br = blockIdx.z;
  const float* src = br ? t1g : t1a;
  const float* wp0 = br ? wg : wa;
  const float bias = br ? bg[co] : ba[co];
  float* dst = br ? grd : att;
  const int tid = threadIdx.x;
  const int py = tid / 24, px = tid - py * 24;
  float acc = bias;
  for (int c0 = 0; c0 < 64; c0 += 16) {
    __syncthreads();
#pragma unroll
    for (int k = 0; k < 16; ++k)
      sx[k * 576 + tid] = src[(n * 64 + c0 + k) * 576 + tid];
    __syncthreads();
#pragma unroll 4
    for (int k = 0; k < 16; ++k) {
      const float* wp = wp0 + (co * 64 + c0 + k) * 9;
#pragma unroll
      for (int dy = 0; dy < 3; ++dy) {
        const int yy = py + dy - 1;
        const bool oky = (unsigned)yy < 24u;
        const int iy = yy < 0 ? 0 : (yy > 23 ? 23 : yy);
#pragma unroll
        for (int dx = 0; dx < 3; ++dx) {
          const int xx = px + dx - 1;
          const bool ok = oky && ((unsigned)xx < 24u);
          const int ix = xx < 0 ? 0 : (xx > 23 ? 23 : xx);
          const float v = ok ? sx[k * 576 + iy * 24 + ix] : 0.f;
          acc += v * wp[dy * 3 + dx];
        }
      }
    }
  }
  if (br == 0) acc = sigmoidf(acc);
  dst[(n * 64 + co) * 576 + tid] = acc;
}

// ---------------------------------------------------------------------------
// SE branch.
// ---------------------------------------------------------------------------
__global__ __launch_bounds__(64) void se_kernel(
    const float* __restrict__ x,
    const float* __restrict__ w1, const float* __restrict__ b1,
    const float* __restrict__ w2, const float* __restrict__ b2,
    float* __restrict__ sev)
{
  __shared__ float pooled[64];
  __shared__ float hid[32];
  const int n = blockIdx.x, t = threadIdx.x;
  const float4* xp4 = (const float4*)(x + (size_t)(n * 64 + t) * 576);
  float s = 0.f;
  for (int p = 0; p < 144; ++p) {
    float4 v = xp4[p];
    s += v.x + v.y + v.z + v.w;
  }
  pooled[t] = s * (1.f / 576.f);
  __syncthreads();
  if (t < 32) {
    float h = b1[t];
    for (int c = 0; c < 64; ++c) h += pooled[c] * w1[t * 64 + c];
    hid[t] = leakyf(h);
  }
  __syncthreads();
  if (t < 16) {
    float v = b2[t];
    for (int j = 0; j < 32; ++j) v += hid[j] * w2[t * 32 + j];
    sev[n * 16 + t] = sigmoidf(v);
  }
}

// ---------------------------------------------------------------------------
// Fused banded Cholesky solver. 384 threads (6 waves) per system b = n*16+g.
// Rank-8 supersteps (72):
//  - REDUNDANT scale: every wave runs the in-register 8-column micro-Cholesky
//    (readlane broadcasts; reads only) -> each wave holds the scaled panel.
//  - Row-oriented update: wave w owns r2 in {8w+8..8w+15}; lane t owns row
//    r1=t. Panel values at lane r2 come via wave-uniform readlane (no LDS).
//    Per lane: 64 readlane + 64 fma + 8 scalar band RMWs (stride-51).
//  - Wave 0 writes scaled columns / RHS fwd-subst / RD during the update
//    phase (its r2<=7 write region is disjoint from all r2>=8 targets).
// Back substitution: 72 rank-8 supersteps, single wave (unchanged from R5).
// ---------------------------------------------------------------------------
__global__ __launch_bounds__(NTH, 1) void chol_kernel(
    const float* __restrict__ att, const float* __restrict__ grd,
    float* __restrict__ sol)
{
  extern __shared__ float S[];          // [28800] band + [NTH] dummy sink
  __shared__ float RHS_s[NUM];
  __shared__ float RD_s[NUM];
  __shared__ float XS_s[NUM];
  __shared__ float DUMW[64];
  const int b = blockIdx.x, tid = threadIdx.x;
  const int t = tid & 63;
  const int n = b >> 4, g = b & 15;
  const float* ac = att + (size_t)(n * 64 + g * 4) * 576;
  const float* gc = grd + (size_t)(n * 64 + g * 4) * 576;
  const int r2base = __builtin_amdgcn_readfirstlane((tid >> 6) * 8 + 8);
  const int dum = NUM * BSTR + tid;
  const bool w0 = (tid < 64);

  // --- zero band
  for (int i = tid; i < NUM * BSTR; i += NTH) S[i] = 0.f;
  __syncthreads();

  // --- assemble band + rhs (verified math)
  for (int i = tid; i < NUM; i += NTH) {
    float diag = 1e-12f, rv = 0.f;
    float od1 = 0.f, od2 = 0.f, od24 = 0.f, od48 = 0.f;
    if (((i + 1) % 24 != 0) && (i + 1 < NUM)) {
      float a0 = ac[0 * 576 + i]; float s = a0 * a0;
      diag += s; rv += s * gc[0 * 576 + i];
    }
    if (i - 1 >= 0 && (i % 24 != 0)) {
      float a0 = ac[0 * 576 + (i - 1)]; float s = a0 * a0;
      diag += s; rv -= s * gc[0 * 576 + (i - 1)]; od1 = -s;
    }
    if (i + 24 < NUM) {
      float a1 = ac[1 * 576 + i]; float s = a1 * a1;
      diag += s; rv += s * gc[1 * 576 + i];
    }
    if (i - 24 >= 0) {
      float a1 = ac[1 * 576 + (i - 24)]; float s = a1 * a1;
      diag += s; rv -= s * gc[1 * 576 + (i - 24)]; od24 = -s;
    }
    if (((i + 2) % 24 != 0) && (i + 2 < NUM)) {
      float a2 = ac[2 * 576 + i]; float s = a2 * a2;
      diag += s; rv += s * gc[2 * 576 + i];
    }
    if (i - 2 >= 0 && (i % 24 != 0)) {
      float a2 = ac[2 * 576 + (i - 2)]; float s = a2 * a2;
      diag += s; rv -= s * gc[2 * 576 + (i - 2)]; od2 = -s;
    }
    if (i + 48 < NUM) {
      float a3 = ac[3 * 576 + i]; float s = a3 * a3;
      diag += s; rv += s * gc[3 * 576 + i];
    }
    if (i - 48 >= 0) {
      float a3 = ac[3 * 576 + (i - 48)]; float s = a3 * a3;
      diag += s; rv -= s * gc[3 * 576 + (i - 48)]; od48 = -s;
    }
    if (i == NUM - 1) {
#pragma unroll
      for (int tt = 0; tt < 4; ++tt) {
        float a = ac[tt * 576 + (NUM - 1)]; float s = a * a;
        diag += s; rv += s * gc[tt * 576 + (NUM - 1)];
      }
    }
    S[i * BSTR + 0] = diag;
    S[i * BSTR + 1] = od1;
    S[i * BSTR + 2] = od2;
    S[i * BSTR + 24] = od24;
    S[i * BSTR + 48] = od48;
    RHS_s[i] = rv;
  }

  // --- factorization: 72 rank-8 supersteps
  for (int j = 0; j < NUM; j += 8) {
    __syncthreads();                     // B1: prev update + wave0 writes done
    const int row = j + t;
    const bool rok = row < NUM;
    // ---- redundant scale (ALL waves; read-only)
    float v[8];
#pragma unroll
    for (int c = 0; c < 8; ++c) {
      const bool okc = rok && (t >= c) && (t - c <= 48);
      float vv = S[okc ? (row * BSTR + (t - c)) : dum];
      v[c] = okc ? vv : 0.f;
    }
    float zb[8], z = 0.f;
    if (w0) {
#pragma unroll
      for (int k = 0; k < 8; ++k) zb[k] = RHS_s[j + k];
      z = RHS_s[rok ? row : j];
      z = rok ? z : 0.f;
    }
    float rdv[8], lp[8][8];
#pragma unroll
    for (int k = 0; k < 8; ++k) {
      const float dk = rdlane(v[k], k);
      rdv[k] = rsqrtf(dk);
      v[k] *= rdv[k];
#pragma unroll
      for (int m = k + 1; m < 8; ++m) {
        lp[m][k] = rdlane(v[k], m);
        v[m] -= v[k] * lp[m][k];
      }
    }
    __syncthreads();                     // B2: all raw panel reads complete
    // ---- wave0: scaled-column writes + fused forward substitution
    if (w0) {
#pragma unroll
      for (int c = 0; c < 8; ++c) {
        const bool okc = rok && (t > c) && (t - c <= 48);
        S[okc ? (row * BSTR + (t - c)) : dum] = v[c];
      }
      float y[8];
      y[0] = zb[0] * rdv[0];
#pragma unroll
      for (int k = 1; k < 8; ++k) {
        float acc = zb[k];
#pragma unroll
        for (int m = 0; m < 8; ++m)
          if (m < k) acc -= lp[k][m] * y[m];
        y[k] = acc * rdv[k];
      }
      if (t < 8) {
        float yv = y[0], rv = rdv[0];
#pragma unroll
        for (int k = 1; k < 8; ++k) {
          yv = (t == k) ? y[k] : yv;
          rv = (t == k) ? rdv[k] : rv;
        }
        RHS_s[row] = yv;
        RD_s[row] = rv;
      } else {
        float zn = z;
#pragma unroll
        for (int c = 0; c < 8; ++c) zn -= v[c] * y[c];
        const bool am = rok && (t <= 55);
        float* rp = am ? &RHS_s[row] : &S[dum];
        *rp = zn;
      }
    }
    // ---- row-oriented rank-8 update (all 6 waves, zero LDS panel traffic)
    {
      float sacc[8];
      int addr[8];
#pragma unroll
      for (int q = 0; q < 8; ++q) {
        const int r2 = r2base + q;
        float s = 0.f;
#pragma unroll
        for (int c = 0; c < 8; ++c) s += rdlane(v[c], r2) * v[c];
        sacc[q] = s;
        const bool valid = rok && (r2 <= t) && (t <= 55);
        addr[q] = valid ? (row * BSTR + (t - r2)) : dum;
      }
      float tv[8];
#pragma unroll
      for (int q = 0; q < 8; ++q) tv[q] = S[addr[q]];
#pragma unroll
      for (int q = 0; q < 8; ++q) S[addr[q]] = tv[q] - sacc[q];
    }
  }
  __syncthreads();

  // --- back substitution: 72 rank-8 supersteps, single wave (as R5)
  if (tid < 64) {
    for (int i = NUM - 1; i >= 7; i -= 8) {
      asm volatile("s_waitcnt lgkmcnt(0)" ::: "memory");
      float zz[8], rr[8];
#pragma unroll
      for (int k = 0; k < 8; ++k) { zz[k] = RHS_s[i - k]; rr[k] = RD_s[i - k]; }
      float L[8][8];
#pragma unroll
      for (int a = 0; a < 8; ++a)
#pragma unroll
        for (int bb = 0; bb < 8; ++bb)
          if (bb > a) L[a][bb] = S[(i - a) * BSTR + (bb - a)];
      float x[8];
      x[0] = zz[0] * rr[0];
#pragma unroll
      for (int k = 1; k < 8; ++k) {
        float acc = zz[k];
#pragma unroll
        for (int m = 0; m < 8; ++m)
          if (m < k) acc -= L[m][k] * x[m];
        x[k] = acc * rr[k];
      }
      const int rb = i - 8 - t;
      const bool bok = rb >= 0;
      float acc2 = 0.f;
#pragma unroll
      for (int k = 0; k < 8; ++k) {
        const int d = 8 + t - k;
        const bool ok = bok && (d <= 48);
        float Lv = S[ok ? ((i - k) * BSTR + d) : (NUM * BSTR + t)];
        Lv = ok ? Lv : 0.f;
        acc2 += Lv * x[k];
      }
      const float zbv = RHS_s[bok ? rb : 0];
      float* rp = bok ? &RHS_s[rb] : &DUMW[t];
      *rp = zbv - acc2;
      float xv = x[0];
#pragma unroll
      for (int k = 1; k < 8; ++k) xv = (t == k) ? x[k] : xv;
      if (t < 8) XS_s[i - t] = xv;
    }
  }
  __syncthreads();
  for (int i = tid; i < NUM; i += NTH) sol[(size_t)b * NUM + i] = XS_s[i];
}

// ---------------------------------------------------------------------------
// GroupNorm(1, GR) + SE scale.
// ---------------------------------------------------------------------------
__global__ __launch_bounds__(256) void gn_kernel(
    const float* __restrict__ sol, const float* __restrict__ sev,
    const float* __restrict__ gnw, const float* __restrict__ gnb,
    float* __restrict__ y)
{
  __shared__ double red[256];
  const int n = blockIdx.x, tid = threadIdx.x;
  const float* sp = sol + (size_t)n * 9216;
  double s = 0.0;
  for (int i = tid; i < 9216; i += 256) s += (double)sp[i];
  red[tid] = s;
  __syncthreads();
  for (int st = 128; st > 0; st >>= 1) {
    if (tid < st) red[tid] += red[tid + st];
    __syncthreads();
  }
  const double mu = red[0] / 9216.0;
  __syncthreads();
  double s2 = 0.0;
  for (int i = tid; i < 9216; i += 256) {
    double dd = (double)sp[i] - mu;
    s2 += dd * dd;
  }
  red[tid] = s2;
  __syncthreads();
  for (int st = 128; st > 0; st >>= 1) {
    if (tid < st) red[tid] += red[tid + st];
    __syncthreads();
  }
  const double var = red[0] / 9216.0;
  const float rstd = (float)(1.0 / sqrt(var + 1e-5));
  const float muf = (float)mu;
  for (int i = tid; i < 9216; i += 256) {
    const int gg = i / 576;
    y[(size_t)n * 9216 + i] =
        ((sp[i] - muf) * rstd * gnw[gg] + gnb[gg]) * sev[n * 16 + gg];
  }
}

// ---------------------------------------------------------------------------
// post conv: (4,16,24,24) -> (4,128,24,24), 3x3 pad1.
// ---------------------------------------------------------------------------
__global__ __launch_bounds__(576) void post_kernel(
    const float* __restrict__ y, const float* __restrict__ w,
    const float* __restrict__ bias, float* __restrict__ out)
{
  __shared__ float sy[16 * 576];
  const int co = blockIdx.x, n = blockIdx.y, tid = threadIdx.x;
#pragma unroll
  for (int k = 0; k < 16; ++k)
    sy[k * 576 + tid] = y[(size_t)(n * 16 + k) * 576 + tid];
  __syncthreads();
  const int py = tid / 24, px = tid - py * 24;
  float acc = bias[co];
#pragma unroll 4
  for (int k = 0; k < 16; ++k) {
    const float* wp = w + (co * 16 + k) * 9;
#pragma unroll
    for (int dy = 0; dy < 3; ++dy) {
      const int yy = py + dy - 1;
      const bool oky = (unsigned)yy < 24u;
      const int iy = yy < 0 ? 0 : (yy > 23 ? 23 : yy);
#pragma unroll
      for (int dx = 0; dx < 3; ++dx) {
        const int xx = px + dx - 1;
        const bool ok = oky && ((unsigned)xx < 24u);
        const int ix = xx < 0 ? 0 : (xx > 23 ? 23 : xx);
        const float v = ok ? sy[k * 576 + iy * 24 + ix] : 0.f;
        acc += v * wp[dy * 3 + dx];
      }
    }
  }
  out[(size_t)(n * 128 + co) * 576 + tid] = acc;
}

// ---------------------------------------------------------------------------
extern "C" void kernel_launch(void* const* d_in, const int* in_sizes, int n_in,
                              void* d_out, int out_size, void* d_ws, size_t ws_size,
                              hipStream_t stream) {
  const float* x       = (const float*)d_in[0];
  const float* grad_w1 = (const float*)d_in[2];
  const float* grad_b1 = (const float*)d_in[3];
  const float* grad_w2 = (const float*)d_in[4];
  const float* grad_b2 = (const float*)d_in[5];
  const float* att_w1  = (const float*)d_in[6];
  const float* att_b1  = (const float*)d_in[7];
  const float* att_w2  = (const float*)d_in[8];
  const float* att_b2  = (const float*)d_in[9];
  const float* se_w1   = (const float*)d_in[10];
  const float* se_b1   = (const float*)d_in[11];
  const float* se_w2   = (const float*)d_in[12];
  const float* se_b2   = (const float*)d_in[13];
  const float* gn_w    = (const float*)d_in[14];
  const float* gn_b    = (const float*)d_in[15];
  const float* post_w  = (const float*)d_in[16];
  const float* post_b  = (const float*)d_in[17];
  float* out = (float*)d_out;

  float* ws  = (float*)d_ws;
  float* t1a = ws;              // 147456
  float* t1g = t1a + 147456;    // 147456
  float* att = t1g + 147456;    // 147456
  float* grd = att + 147456;    // 147456
  float* sev = grd + 147456;    // 64
  float* sol = sev + 64;        // 36864
  float* yb  = sol + 36864;     // 36864

  (void)hipFuncSetAttribute((const void*)chol_kernel,
                            hipFuncAttributeMaxDynamicSharedMemorySize,
                            (int)CHOL_LDS_BYTES);

  conv1_kernel<<<dim3(64, 4), 576, 0, stream>>>(x, att_w1, att_b1,
                                                grad_w1, grad_b1, t1a, t1g);
  se_kernel<<<4, 64, 0, stream>>>(x, se_w1, se_b1, se_w2, se_b2, sev);
  conv2_kernel<<<dim3(64, 4, 2), 576, 0, stream>>>(t1a, t1g, att_w2, att_b2,
                                                   grad_w2, grad_b2, att, grd);
  chol_kernel<<<64, NTH, CHOL_LDS_BYTES, stream>>>(att, grd, sol);
  gn_kernel<<<4, 256, 0, stream>>>(sol, sev, gn_w, gn_b, yb);
  post_kernel<<<dim3(128, 4), 576, 0, stream>>>(yb, post_w, post_b, out);
}

// Round 7
// 231.931 us; speedup vs baseline: 1.1504x; 1.1504x over previous
//
#include <hip/hip_runtime.h>
#include <math.h>

#define NUM 576
#define BSTR 50
#define CTH 256
// dynamic LDS: band (576*50) + 256-float dummy sink
#define CHOL_LDS_BYTES ((NUM * BSTR + CTH) * sizeof(float))
// CP swizzle: keeps even alignment (r even), spreads banks across lane groups
#define SIDX(r) ((r) + 2 * ((r) >> 3))

__device__ __forceinline__ float leakyf(float v) { return v > 0.f ? v : 0.01f * v; }
__device__ __forceinline__ float sigmoidf(float v) { return 1.f / (1.f + __expf(-v)); }

// ---------------------------------------------------------------------------
// conv1 + SE fused. Grid (65, 4): blocks co<64 do the dual-branch 3x3 conv;
// block co==64 does the SE branch and zeroes the gn stat accumulators.
// ---------------------------------------------------------------------------
__global__ __launch_bounds__(576) void conv1se_kernel(
    const float* __restrict__ x,
    const float* __restrict__ wa, const float* __restrict__ ba,
    const float* __restrict__ wg, const float* __restrict__ bg,
    const float* __restrict__ sw1, const float* __restrict__ sb1,
    const float* __restrict__ sw2, const float* __restrict__ sb2,
    float* __restrict__ outa, float* __restrict__ outg,
    float* __restrict__ sev, double* __restrict__ acc)
{
  __shared__ float sx[16 * 576];
  __shared__ float pooled[64];
  __shared__ float hid[32];
  const int co = blockIdx.x, n = blockIdx.y;
  const int tid = threadIdx.x;

  if (co == 64) {
    // ---- SE path + stat-accumulator zeroing
    if (tid < 2) acc[n * 2 + tid] = 0.0;
    if (tid < 64) {
      const float4* xp4 = (const float4*)(x + (size_t)(n * 64 + tid) * 576);
      float s = 0.f;
      for (int p = 0; p < 144; ++p) {
        float4 v = xp4[p];
        s += v.x + v.y + v.z + v.w;
      }
      pooled[tid] = s * (1.f / 576.f);
    }
    __syncthreads();
    if (tid < 32) {
      float h = sb1[tid];
      for (int c = 0; c < 64; ++c) h += pooled[c] * sw1[tid * 64 + c];
      hid[tid] = leakyf(h);
    }
    __syncthreads();
    if (tid < 16) {
      float v = sb2[tid];
      for (int j = 0; j < 32; ++j) v += hid[j] * sw2[tid * 32 + j];
      sev[n * 16 + tid] = sigmoidf(v);
    }
    return;
  }

  const int py = tid / 24, px = tid - py * 24;
  float acc_a = ba[co];
  float acc_g = bg[co];
  for (int c0 = 0; c0 < 64; c0 += 16) {
    __syncthreads();
    {
      const float4* xs4 = (const float4*)(x + (size_t)(n * 64 + c0) * 576);
      float4* sx4 = (float4*)sx;
#pragma unroll
      for (int q = 0; q < 4; ++q) sx4[tid + q * 576] = xs4[tid + q * 576];
    }
    __syncthreads();
#pragma unroll 4
    for (int k = 0; k < 16; ++k) {
      const float* wpa = wa + (co * 64 + c0 + k) * 9;
      const float* wpg = wg + (co * 64 + c0 + k) * 9;
#pragma unroll
      for (int dy = 0; dy < 3; ++dy) {
        const int yy = py + dy - 1;
        const bool oky = (unsigned)yy < 24u;
        const int iy = yy < 0 ? 0 : (yy > 23 ? 23 : yy);
#pragma unroll
        for (int dx = 0; dx < 3; ++dx) {
          const int xx = px + dx - 1;
          const bool ok = oky && ((unsigned)xx < 24u);
          const int ix = xx < 0 ? 0 : (xx > 23 ? 23 : xx);
          const float v = ok ? sx[k * 576 + iy * 24 + ix] : 0.f;
          acc_a += v * wpa[dy * 3 + dx];
          acc_g += v * wpg[dy * 3 + dx];
        }
      }
    }
  }
  const int o = (n * 64 + co) * 576 + tid;
  outa[o] = leakyf(acc_a);
  outg[o] = leakyf(acc_g);
}

// ---------------------------------------------------------------------------
// conv2: second 3x3 conv per branch. blockIdx.z selects branch.
// ---------------------------------------------------------------------------
__global__ __launch_bounds__(576) void conv2_kernel(
    const float* __restrict__ t1a, const float* __restrict__ t1g,
    const float* __restrict__ wa, const float* __restrict__ ba,
    const float* __restrict__ wg, const float* __restrict__ bg,
    float* __restrict__ att, float* __restrict__ grd)
{
  __shared__ float sx[16 * 576];
  const int co = blockIdx.x, n = blockIdx.y, br = blockIdx.z;
  const float* src = br ? t1g : t1a;
  const float* wp0 = br ? wg : wa;
  const float bias = br ? bg[co] : ba[co];
  float* dst = br ? grd : att;
  const int tid = threadIdx.x;
  const int py = tid / 24, px = tid - py * 24;
  float acc = bias;
  for (int c0 = 0; c0 < 64; c0 += 16) {
    __syncthreads();
    {
      const float4* s4 = (const float4*)(src + (size_t)(n * 64 + c0) * 576);
      float4* sx4 = (float4*)sx;
#pragma unroll
      for (int q = 0; q < 4; ++q) sx4[tid + q * 576] = s4[tid + q * 576];
    }
    __syncthreads();
#pragma unroll 4
    for (int k = 0; k < 16; ++k) {
      const float* wp = wp0 + (co * 64 + c0 + k) * 9;
#pragma unroll
      for (int dy = 0; dy < 3; ++dy) {
        const int yy = py + dy - 1;
        const bool oky = (unsigned)yy < 24u;
        const int iy = yy < 0 ? 0 : (yy > 23 ? 23 : yy);
#pragma unroll
        for (int dx = 0; dx < 3; ++dx) {
          const int xx = px + dx - 1;
          const bool ok = oky && ((unsigned)xx < 24u);
          const int ix = xx < 0 ? 0 : (xx > 23 ? 23 : xx);
          const float v = ok ? sx[k * 576 + iy * 24 + ix] : 0.f;
          acc += v * wp[dy * 3 + dx];
        }
      }
    }
  }
  if (br == 0) acc = sigmoidf(acc);
  dst[(n * 64 + co) * 576 + tid] = acc;
}

// ---------------------------------------------------------------------------
// Fused banded Cholesky solver (R5 structure: rank-8 supersteps, wave-0
// in-register micro-Cholesky, 2x2-tiled trailing update) + swizzled CP panel
// + per-n GroupNorm stat accumulation (double atomics).
// ---------------------------------------------------------------------------
__global__ __launch_bounds__(CTH, 1) void chol_kernel(
    const float* __restrict__ att, const float* __restrict__ grd,
    float* __restrict__ sol, double* __restrict__ acc)
{
  extern __shared__ float S[];          // [28800] band + [256] dummy sink
  __shared__ float RHS_s[NUM];
  __shared__ float RD_s[NUM];
  __shared__ float XS_s[NUM];
  __shared__ __align__(16) float CP[8][80];   // swizzled scaled panel columns
  __shared__ float DUMW[64];
  __shared__ double RW[8];
  const int b = blockIdx.x, tid = threadIdx.x;
  const int n = b >> 4, g = b & 15;
  const float* ac = att + (size_t)(n * 64 + g * 4) * 576;
  const float* gc = grd + (size_t)(n * 64 + g * 4) * 576;

  // --- 2x2 tile decode: triangle (U,W), 0<=W<=U<=23, T = U(U+1)/2 + W.
  int r1A, r2A, r1B, r2B;
  bool tokB;
  {
    int T = tid;
    int U = (int)((sqrtf(8.f * (float)T + 1.f) - 1.f) * 0.5f);
    while (U * (U + 1) / 2 > T) --U;
    while ((U + 1) * (U + 2) / 2 <= T) ++U;
    int W = T - U * (U + 1) / 2;
    r1A = 8 + 2 * U; r2A = 8 + 2 * W;
    tokB = (tid >= 212);
    T = tokB ? (tid + 44) : 0;
    U = (int)((sqrtf(8.f * (float)T + 1.f) - 1.f) * 0.5f);
    while (U * (U + 1) / 2 > T) --U;
    while ((U + 1) * (U + 2) / 2 <= T) ++U;
    W = T - U * (U + 1) / 2;
    r1B = 8 + 2 * U; r2B = 8 + 2 * W;
  }

  // --- zero band
  for (int i = tid; i < NUM * BSTR; i += CTH) S[i] = 0.f;
  __syncthreads();

  // --- assemble band + rhs (verified math), seed rd[0]
  for (int i = tid; i < NUM; i += CTH) {
    float diag = 1e-12f, rv = 0.f;
    float od1 = 0.f, od2 = 0.f, od24 = 0.f, od48 = 0.f;
    if (((i + 1) % 24 != 0) && (i + 1 < NUM)) {
      float a0 = ac[0 * 576 + i]; float s = a0 * a0;
      diag += s; rv += s * gc[0 * 576 + i];
    }
    if (i - 1 >= 0 && (i % 24 != 0)) {
      float a0 = ac[0 * 576 + (i - 1)]; float s = a0 * a0;
      diag += s; rv -= s * gc[0 * 576 + (i - 1)]; od1 = -s;
    }
    if (i + 24 < NUM) {
      float a1 = ac[1 * 576 + i]; float s = a1 * a1;
      diag += s; rv += s * gc[1 * 576 + i];
    }
    if (i - 24 >= 0) {
      float a1 = ac[1 * 576 + (i - 24)]; float s = a1 * a1;
      diag += s; rv -= s * gc[1 * 576 + (i - 24)]; od24 = -s;
    }
    if (((i + 2) % 24 != 0) && (i + 2 < NUM)) {
      float a2 = ac[2 * 576 + i]; float s = a2 * a2;
      diag += s; rv += s * gc[2 * 576 + i];
    }
    if (i - 2 >= 0 && (i % 24 != 0)) {
      float a2 = ac[2 * 576 + (i - 2)]; float s = a2 * a2;
      diag += s; rv -= s * gc[2 * 576 + (i - 2)]; od2 = -s;
    }
    if (i + 48 < NUM) {
      float a3 = ac[3 * 576 + i]; float s = a3 * a3;
      diag += s; rv += s * gc[3 * 576 + i];
    }
    if (i - 48 >= 0) {
      float a3 = ac[3 * 576 + (i - 48)]; float s = a3 * a3;
      diag += s; rv -= s * gc[3 * 576 + (i - 48)]; od48 = -s;
    }
    if (i == NUM - 1) {
#pragma unroll
      for (int t = 0; t < 4; ++t) {
        float a = ac[t * 576 + (NUM - 1)]; float s = a * a;
        diag += s; rv += s * gc[t * 576 + (NUM - 1)];
      }
    }
    S[i * BSTR + 0] = diag;
    S[i * BSTR + 1] = od1;
    S[i * BSTR + 2] = od2;
    S[i * BSTR + 24] = od24;
    S[i * BSTR + 48] = od48;
    RHS_s[i] = rv;
    if (i == 0) RD_s[0] = rsqrtf(diag);
  }

  // --- factorization: 72 rank-8 supersteps
  for (int j = 0; j < NUM; j += 8) {
    __syncthreads();
    // ---- scale phase: wave 0, in-register 8-col micro-Cholesky
    if (tid < 64) {
      const int t = tid;
      const int row = j + t;
      const bool rok = row < NUM;
      float v[8];
#pragma unroll
      for (int c = 0; c < 8; ++c) {
        const bool okc = rok && (t >= c) && (t - c <= 48);
        const int addr = okc ? (row * BSTR + (t - c)) : (NUM * BSTR + t);
        float vv = S[addr];
        v[c] = okc ? vv : 0.f;
      }
      float zb[8];
#pragma unroll
      for (int k = 0; k < 8; ++k) zb[k] = RHS_s[j + k];
      float z = RHS_s[rok ? row : j];
      z = rok ? z : 0.f;
      const float rd0 = RD_s[j];
      float rdv[8], y[8], lp[8][8];
#pragma unroll
      for (int k = 0; k < 8; ++k) {
        if (k == 0) {
          rdv[0] = rd0;
        } else {
          const float dk = __shfl(v[k], k);
          rdv[k] = rsqrtf(dk);
        }
        v[k] *= rdv[k];
#pragma unroll
        for (int m = k + 1; m < 8; ++m) {
          lp[m][k] = __shfl(v[k], m);
          v[m] -= v[k] * lp[m][k];
        }
      }
      // fused forward substitution (uniform scalars)
      y[0] = zb[0] * rdv[0];
#pragma unroll
      for (int k = 1; k < 8; ++k) {
        float a = zb[k];
#pragma unroll
        for (int m = 0; m < 8; ++m)
          if (m < k) a -= lp[k][m] * y[m];
        y[k] = a * rdv[k];
      }
      float zn = z;
#pragma unroll
      for (int c = 0; c < 8; ++c) zn -= v[c] * y[c];
      // stores: scaled columns to band + swizzled CP panel
#pragma unroll
      for (int c = 0; c < 8; ++c) {
        const bool okc = rok && (t > c) && (t - c <= 48);
        float* bp = okc ? &S[row * BSTR + (t - c)] : &S[NUM * BSTR + t];
        *bp = v[c];
        CP[c][SIDX(t)] = okc ? v[c] : 0.f;
      }
      if (t < 8) {
        float yv = y[0], rv = rdv[0];
#pragma unroll
        for (int k = 1; k < 8; ++k) {
          yv = (t == k) ? y[k] : yv;
          rv = (t == k) ? rdv[k] : rv;
        }
        RHS_s[row] = yv;
        RD_s[row] = rv;
      } else {
        float* rp = rok ? &RHS_s[row] : &DUMW[t & 63];
        *rp = zn;
      }
    }
    __syncthreads();
    // ---- rank-8 trailing update: 2x2 tiles, swizzled CP reads
    const int R = (NUM - 1) - j;
    {
      const bool a0 = (r1A <= R);
      const bool a1 = (r1A + 1 <= R);
      float2 cr[8], cc[8];
#pragma unroll
      for (int c = 0; c < 8; ++c) {
        cr[c] = *(const float2*)&CP[c][SIDX(r1A)];
        cc[c] = *(const float2*)&CP[c][SIDX(r2A)];
      }
      float s00 = 0.f, s01 = 0.f, s10 = 0.f, s11 = 0.f;
#pragma unroll
      for (int c = 0; c < 8; ++c) {
        s00 += cr[c].x * cc[c].x; s01 += cr[c].x * cc[c].y;
        s10 += cr[c].y * cc[c].x; s11 += cr[c].y * cc[c].y;
      }
      const int p00 = j * BSTR + 51 * r1A - r2A;
      float* q00 = a0 ? &S[p00] : &S[NUM * BSTR + tid];
      float* q01 = a0 ? &S[p00 - 1] : &S[NUM * BSTR + tid];
      float* q10 = a1 ? &S[p00 + 51] : &S[NUM * BSTR + tid];
      float* q11 = a1 ? &S[p00 + 50] : &S[NUM * BSTR + tid];
      const float t00 = *q00 - s00, t01 = *q01 - s01;
      const float t10 = *q10 - s10, t11 = *q11 - s11;
      *q00 = t00; *q01 = t01; *q10 = t10; *q11 = t11;
      if (tid == 0 && a0)                  // tile (8,8): d_{j+8} final
        RD_s[j + 8] = rsqrtf(t00);
    }
    {
      const bool a0 = tokB && (r1B <= R);
      const bool a1 = tokB && (r1B + 1 <= R);
      float2 cr[8], cc[8];
#pragma unroll
      for (int c = 0; c < 8; ++c) {
        cr[c] = *(const float2*)&CP[c][SIDX(r1B)];
        cc[c] = *(const float2*)&CP[c][SIDX(r2B)];
      }
      float s00 = 0.f, s01 = 0.f, s10 = 0.f, s11 = 0.f;
#pragma unroll
      for (int c = 0; c < 8; ++c) {
        s00 += cr[c].x * cc[c].x; s01 += cr[c].x * cc[c].y;
        s10 += cr[c].y * cc[c].x; s11 += cr[c].y * cc[c].y;
      }
      const int p00 = j * BSTR + 51 * r1B - r2B;
      float* q00 = a0 ? &S[p00] : &S[NUM * BSTR + tid];
      float* q01 = a0 ? &S[p00 - 1] : &S[NUM * BSTR + tid];
      float* q10 = a1 ? &S[p00 + 51] : &S[NUM * BSTR + tid];
      float* q11 = a1 ? &S[p00 + 50] : &S[NUM * BSTR + tid];
      const float t00 = *q00 - s00, t01 = *q01 - s01;
      const float t10 = *q10 - s10, t11 = *q11 - s11;
      *q00 = t00; *q01 = t01; *q10 = t10; *q11 = t11;
    }
  }
  __syncthreads();

  // --- back substitution: 72 rank-8 supersteps, single wave
  if (tid < 64) {
    const int t = tid;
    for (int i = NUM - 1; i >= 7; i -= 8) {
      asm volatile("s_waitcnt lgkmcnt(0)" ::: "memory");
      float zz[8], rr[8];
#pragma unroll
      for (int k = 0; k < 8; ++k) { zz[k] = RHS_s[i - k]; rr[k] = RD_s[i - k]; }
      float L[8][8];
#pragma unroll
      for (int a = 0; a < 8; ++a)
#pragma unroll
        for (int bb = 0; bb < 8; ++bb)
          if (bb > a) L[a][bb] = S[(i - a) * BSTR + (bb - a)];
      float x[8];
      x[0] = zz[0] * rr[0];
#pragma unroll
      for (int k = 1; k < 8; ++k) {
        float a = zz[k];
#pragma unroll
        for (int m = 0; m < 8; ++m)
          if (m < k) a -= L[m][k] * x[m];
        x[k] = a * rr[k];
      }
      const int rb = i - 8 - t;
      const bool bok = rb >= 0;
      float acc2 = 0.f;
#pragma unroll
      for (int k = 0; k < 8; ++k) {
        const int d = 8 + t - k;
        const bool ok = bok && (d <= 48);
        float Lv = S[ok ? ((i - k) * BSTR + d) : (NUM * BSTR + t)];
        Lv = ok ? Lv : 0.f;
        acc2 += Lv * x[k];
      }
      const float zbv = RHS_s[bok ? rb : 0];
      float* rp = bok ? &RHS_s[rb] : &DUMW[t];
      *rp = zbv - acc2;
      float xv = x[0];
#pragma unroll
      for (int k = 1; k < 8; ++k) xv = (t == k) ? x[k] : xv;
      if (t < 8) XS_s[i - t] = xv;
    }
  }
  __syncthreads();

  // --- write solution + accumulate GroupNorm stats (double)
  double ls = 0.0, ls2 = 0.0;
  for (int i = tid; i < NUM; i += CTH) {
    const float xv = XS_s[i];
    sol[(size_t)b * NUM + i] = xv;
    ls += (double)xv;
    ls2 += (double)xv * (double)xv;
  }
#pragma unroll
  for (int off = 32; off > 0; off >>= 1) {
    ls += __shfl_down(ls, off);
    ls2 += __shfl_down(ls2, off);
  }
  if ((tid & 63) == 0) {
    RW[(tid >> 6) * 2] = ls;
    RW[(tid >> 6) * 2 + 1] = ls2;
  }
  __syncthreads();
  if (tid == 0) {
    const double s = RW[0] + RW[2] + RW[4] + RW[6];
    const double s2 = RW[1] + RW[3] + RW[5] + RW[7];
    atomicAdd(&acc[n * 2], s);
    atomicAdd(&acc[n * 2 + 1], s2);
  }
}

// ---------------------------------------------------------------------------
// post conv fused with GroupNorm-apply + SE scale:
// y = ((sol - mu)*rstd*gnw[k] + gnb[k]) * sev[k] applied during staging,
// then 3x3 pad1 conv (4,16,24,24) -> (4,128,24,24).
// ---------------------------------------------------------------------------
__global__ __launch_bounds__(576) void postgn_kernel(
    const float* __restrict__ sol, const double* __restrict__ acc,
    const float* __restrict__ sev,
    const float* __restrict__ gnw, const float* __restrict__ gnb,
    const float* __restrict__ w, const float* __restrict__ bias,
    float* __restrict__ out)
{
  __shared__ float sy[16 * 576];
  const int co = blockIdx.x, n = blockIdx.y, tid = threadIdx.x;
  const double mu_d = acc[n * 2] * (1.0 / 9216.0);
  const double var_d = acc[n * 2 + 1] * (1.0 / 9216.0) - mu_d * mu_d;
  const float rstd = (float)(1.0 / sqrt(var_d + 1e-5));
  const float muf = (float)mu_d;
  {
    const float4* sp4 = (const float4*)(sol + (size_t)n * 9216);
    float4* sy4 = (float4*)sy;
#pragma unroll
    for (int q = 0; q < 4; ++q) {
      const int p = tid + q * 576;          // 2304 float4s; 144 per channel
      const int k = p / 144;
      const float sv = sev[n * 16 + k];
      const float A = rstd * gnw[k] * sv;
      const float B = (gnb[k] - muf * rstd * gnw[k]) * sv;
      float4 v = sp4[p];
      v.x = v.x * A + B; v.y = v.y * A + B;
      v.z = v.z * A + B; v.w = v.w * A + B;
      sy4[p] = v;
    }
  }
  __syncthreads();
  const int py = tid / 24, px = tid - py * 24;
  float a = bias[co];
#pragma unroll 4
  for (int k = 0; k < 16; ++k) {
    const float* wp = w + (co * 16 + k) * 9;
#pragma unroll
    for (int dy = 0; dy < 3; ++dy) {
      const int yy = py + dy - 1;
      const bool oky = (unsigned)yy < 24u;
      const int iy = yy < 0 ? 0 : (yy > 23 ? 23 : yy);
#pragma unroll
      for (int dx = 0; dx < 3; ++dx) {
        const int xx = px + dx - 1;
        const bool ok = oky && ((unsigned)xx < 24u);
        const int ix = xx < 0 ? 0 : (xx > 23 ? 23 : xx);
        const float v = ok ? sy[k * 576 + iy * 24 + ix] : 0.f;
        a += v * wp[dy * 3 + dx];
      }
    }
  }
  out[(size_t)(n * 128 + co) * 576 + tid] = a;
}

// ---------------------------------------------------------------------------
extern "C" void kernel_launch(void* const* d_in, const int* in_sizes, int n_in,
                              void* d_out, int out_size, void* d_ws, size_t ws_size,
                              hipStream_t stream) {
  const float* x       = (const float*)d_in[0];
  const float* grad_w1 = (const float*)d_in[2];
  const float* grad_b1 = (const float*)d_in[3];
  const float* grad_w2 = (const float*)d_in[4];
  const float* grad_b2 = (const float*)d_in[5];
  const float* att_w1  = (const float*)d_in[6];
  const float* att_b1  = (const float*)d_in[7];
  const float* att_w2  = (const float*)d_in[8];
  const float* att_b2  = (const float*)d_in[9];
  const float* se_w1   = (const float*)d_in[10];
  const float* se_b1   = (const float*)d_in[11];
  const float* se_w2   = (const float*)d_in[12];
  const float* se_b2   = (const float*)d_in[13];
  const float* gn_w    = (const float*)d_in[14];
  const float* gn_b    = (const float*)d_in[15];
  const float* post_w  = (const float*)d_in[16];
  const float* post_b  = (const float*)d_in[17];
  float* out = (float*)d_out;

  float* ws  = (float*)d_ws;
  float* t1a = ws;              // 147456
  float* t1g = t1a + 147456;    // 147456
  float* att = t1g + 147456;    // 147456
  float* grd = att + 147456;    // 147456
  float* sev = grd + 147456;    // 64
  float* sol = sev + 64;        // 36864
  double* acc = (double*)(sol + 36864);  // 8 doubles (8B-aligned: even offset)

  (void)hipFuncSetAttribute((const void*)chol_kernel,
                            hipFuncAttributeMaxDynamicSharedMemorySize,
                            (int)CHOL_LDS_BYTES);

  conv1se_kernel<<<dim3(65, 4), 576, 0, stream>>>(
      x, att_w1, att_b1, grad_w1, grad_b1,
      se_w1, se_b1, se_w2, se_b2, t1a, t1g, sev, acc);
  conv2_kernel<<<dim3(64, 4, 2), 576, 0, stream>>>(t1a, t1g, att_w2, att_b2,
                                                   grad_w2, grad_b2, att, grd);
  chol_kernel<<<64, CTH, CHOL_LDS_BYTES, stream>>>(att, grd, sol, acc);
  postgn_kernel<<<dim3(128, 4), 576, 0, stream>>>(sol, acc, sev, gn_w, gn_b,
                                                  post_w, post_b, out);
}

// Round 8
// 198.806 us; speedup vs baseline: 1.3421x; 1.1666x over previous
//
#include <hip/hip_runtime.h>
#include <math.h>

#define NUM 576
#define BSTR 50
#define CTH 512
// dynamic LDS: band (576*50) + CTH-float dummy sink
#define CHOL_LDS_BYTES ((NUM * BSTR + CTH) * sizeof(float))

__device__ __forceinline__ float leakyf(float v) { return v > 0.f ? v : 0.01f * v; }
__device__ __forceinline__ float sigmoidf(float v) { return 1.f / (1.f + __expf(-v)); }
__device__ __forceinline__ float rdlane(float v, int l) {
  return __uint_as_float(__builtin_amdgcn_readlane(__float_as_uint(v), l));
}

// ---------------------------------------------------------------------------
// conv1 + SE fused. Grid (65, 4): blocks co<64 do the dual-branch 3x3 conv;
// block co==64 does the SE branch and zeroes the gn stat accumulators.
// ---------------------------------------------------------------------------
__global__ __launch_bounds__(576) void conv1se_kernel(
    const float* __restrict__ x,
    const float* __restrict__ wa, const float* __restrict__ ba,
    const float* __restrict__ wg, const float* __restrict__ bg,
    const float* __restrict__ sw1, const float* __restrict__ sb1,
    const float* __restrict__ sw2, const float* __restrict__ sb2,
    float* __restrict__ outa, float* __restrict__ outg,
    float* __restrict__ sev, double* __restrict__ acc)
{
  __shared__ float sx[16 * 576];
  __shared__ float pooled[64];
  __shared__ float hid[32];
  const int co = blockIdx.x, n = blockIdx.y;
  const int tid = threadIdx.x;

  if (co == 64) {
    if (tid < 2) acc[n * 2 + tid] = 0.0;
    if (tid < 64) {
      const float4* xp4 = (const float4*)(x + (size_t)(n * 64 + tid) * 576);
      float s = 0.f;
      for (int p = 0; p < 144; ++p) {
        float4 v = xp4[p];
        s += v.x + v.y + v.z + v.w;
      }
      pooled[tid] = s * (1.f / 576.f);
    }
    __syncthreads();
    if (tid < 32) {
      float h = sb1[tid];
      for (int c = 0; c < 64; ++c) h += pooled[c] * sw1[tid * 64 + c];
      hid[tid] = leakyf(h);
    }
    __syncthreads();
    if (tid < 16) {
      float v = sb2[tid];
      for (int j = 0; j < 32; ++j) v += hid[j] * sw2[tid * 32 + j];
      sev[n * 16 + tid] = sigmoidf(v);
    }
    return;
  }

  const int py = tid / 24, px = tid - py * 24;
  float acc_a = ba[co];
  float acc_g = bg[co];
  for (int c0 = 0; c0 < 64; c0 += 16) {
    __syncthreads();
    {
      const float4* xs4 = (const float4*)(x + (size_t)(n * 64 + c0) * 576);
      float4* sx4 = (float4*)sx;
#pragma unroll
      for (int q = 0; q < 4; ++q) sx4[tid + q * 576] = xs4[tid + q * 576];
    }
    __syncthreads();
#pragma unroll 4
    for (int k = 0; k < 16; ++k) {
      const float* wpa = wa + (co * 64 + c0 + k) * 9;
      const float* wpg = wg + (co * 64 + c0 + k) * 9;
#pragma unroll
      for (int dy = 0; dy < 3; ++dy) {
        const int yy = py + dy - 1;
        const bool oky = (unsigned)yy < 24u;
        const int iy = yy < 0 ? 0 : (yy > 23 ? 23 : yy);
#pragma unroll
        for (int dx = 0; dx < 3; ++dx) {
          const int xx = px + dx - 1;
          const bool ok = oky && ((unsigned)xx < 24u);
          const int ix = xx < 0 ? 0 : (xx > 23 ? 23 : xx);
          const float v = ok ? sx[k * 576 + iy * 24 + ix] : 0.f;
          acc_a += v * wpa[dy * 3 + dx];
          acc_g += v * wpg[dy * 3 + dx];
        }
      }
    }
  }
  const int o = (n * 64 + co) * 576 + tid;
  outa[o] = leakyf(acc_a);
  outg[o] = leakyf(acc_g);
}

// ---------------------------------------------------------------------------
// conv2: second 3x3 conv per branch. blockIdx.z selects branch.
// ---------------------------------------------------------------------------
__global__ __launch_bounds__(576) void conv2_kernel(
    const float* __restrict__ t1a, const float* __restrict__ t1g,
    const float* __restrict__ wa, const float* __restrict__ ba,
    const float* __restrict__ wg, const float* __restrict__ bg,
    float* __restrict__ att, float* __restrict__ grd)
{
  __shared__ float sx[16 * 576];
  const int co = blockIdx.x, n = blockIdx.y, br = blockIdx.z;
  const float* src = br ? t1g : t1a;
  const float* wp0 = br ? wg : wa;
  const float bias = br ? bg[co] : ba[co];
  float* dst = br ? grd : att;
  const int tid = threadIdx.x;
  const int py = tid / 24, px = tid - py * 24;
  float acc = bias;
  for (int c0 = 0; c0 < 64; c0 += 16) {
    __syncthreads();
    {
      const float4* s4 = (const float4*)(src + (size_t)(n * 64 + c0) * 576);
      float4* sx4 = (float4*)sx;
#pragma unroll
      for (int q = 0; q < 4; ++q) sx4[tid + q * 576] = s4[tid + q * 576];
    }
    __syncthreads();
#pragma unroll 4
    for (int k = 0; k < 16; ++k) {
      const float* wp = wp0 + (co * 64 + c0 + k) * 9;
#pragma unroll
      for (int dy = 0; dy < 3; ++dy) {
        const int yy = py + dy - 1;
        const bool oky = (unsigned)yy < 24u;
        const int iy = yy < 0 ? 0 : (yy > 23 ? 23 : yy);
#pragma unroll
        for (int dx = 0; dx < 3; ++dx) {
          const int xx = px + dx - 1;
          const bool ok = oky && ((unsigned)xx < 24u);
          const int ix = xx < 0 ? 0 : (xx > 23 ? 23 : xx);
          const float v = ok ? sx[k * 576 + iy * 24 + ix] : 0.f;
          acc += v * wp[dy * 3 + dx];
        }
      }
    }
  }
  if (br == 0) acc = sigmoidf(acc);
  dst[(n * 64 + co) * 576 + tid] = acc;
}

// ---------------------------------------------------------------------------
// Fused banded Cholesky solver. 512 threads (8 waves) per system b = n*16+g.
// R5 structure: rank-8 supersteps, wave-0 in-register micro-Cholesky with
// readlane broadcasts, 2x2-tiled trailing update (now 1 tile/thread over
// 8 waves), rank-8 back substitution. + GroupNorm stat accumulation.
// ---------------------------------------------------------------------------
__global__ __launch_bounds__(CTH, 1) void chol_kernel(
    const float* __restrict__ att, const float* __restrict__ grd,
    float* __restrict__ sol, double* __restrict__ acc)
{
  extern __shared__ float S[];          // [28800] band + [CTH] dummy sink
  __shared__ float RHS_s[NUM];
  __shared__ float RD_s[NUM];
  __shared__ float XS_s[NUM];
  __shared__ __align__(16) float CP[8][64];   // scaled panel columns
  __shared__ float DUMW[64];
  __shared__ double RW[16];
  const int b = blockIdx.x, tid = threadIdx.x;
  const int n = b >> 4, g = b & 15;
  const float* ac = att + (size_t)(n * 64 + g * 4) * 576;
  const float* gc = grd + (size_t)(n * 64 + g * 4) * 576;

  // --- 2x2 tile decode: triangle (U,W), 0<=W<=U<=23, T = U(U+1)/2 + W.
  // One tile per thread: T = tid for tid < 300, else inactive sentinel.
  int r1A, r2A;
  {
    const int T = (tid < 300) ? tid : 0;
    int U = (int)((sqrtf(8.f * (float)T + 1.f) - 1.f) * 0.5f);
    while (U * (U + 1) / 2 > T) --U;
    while ((U + 1) * (U + 2) / 2 <= T) ++U;
    const int W = T - U * (U + 1) / 2;
    r1A = (tid < 300) ? (8 + 2 * U) : 63;   // 63 -> never active
    r2A = 8 + 2 * W;
  }

  // --- zero band
  for (int i = tid; i < NUM * BSTR; i += CTH) S[i] = 0.f;
  __syncthreads();

  // --- assemble band + rhs (verified math), seed rd[0]
  for (int i = tid; i < NUM; i += CTH) {
    float diag = 1e-12f, rv = 0.f;
    float od1 = 0.f, od2 = 0.f, od24 = 0.f, od48 = 0.f;
    if (((i + 1) % 24 != 0) && (i + 1 < NUM)) {
      float a0 = ac[0 * 576 + i]; float s = a0 * a0;
      diag += s; rv += s * gc[0 * 576 + i];
    }
    if (i - 1 >= 0 && (i % 24 != 0)) {
      float a0 = ac[0 * 576 + (i - 1)]; float s = a0 * a0;
      diag += s; rv -= s * gc[0 * 576 + (i - 1)]; od1 = -s;
    }
    if (i + 24 < NUM) {
      float a1 = ac[1 * 576 + i]; float s = a1 * a1;
      diag += s; rv += s * gc[1 * 576 + i];
    }
    if (i - 24 >= 0) {
      float a1 = ac[1 * 576 + (i - 24)]; float s = a1 * a1;
      diag += s; rv -= s * gc[1 * 576 + (i - 24)]; od24 = -s;
    }
    if (((i + 2) % 24 != 0) && (i + 2 < NUM)) {
      float a2 = ac[2 * 576 + i]; float s = a2 * a2;
      diag += s; rv += s * gc[2 * 576 + i];
    }
    if (i - 2 >= 0 && (i % 24 != 0)) {
      float a2 = ac[2 * 576 + (i - 2)]; float s = a2 * a2;
      diag += s; rv -= s * gc[2 * 576 + (i - 2)]; od2 = -s;
    }
    if (i + 48 < NUM) {
      float a3 = ac[3 * 576 + i]; float s = a3 * a3;
      diag += s; rv += s * gc[3 * 576 + i];
    }
    if (i - 48 >= 0) {
      float a3 = ac[3 * 576 + (i - 48)]; float s = a3 * a3;
      diag += s; rv -= s * gc[3 * 576 + (i - 48)]; od48 = -s;
    }
    if (i == NUM - 1) {
#pragma unroll
      for (int t = 0; t < 4; ++t) {
        float a = ac[t * 576 + (NUM - 1)]; float s = a * a;
        diag += s; rv += s * gc[t * 576 + (NUM - 1)];
      }
    }
    S[i * BSTR + 0] = diag;
    S[i * BSTR + 1] = od1;
    S[i * BSTR + 2] = od2;
    S[i * BSTR + 24] = od24;
    S[i * BSTR + 48] = od48;
    RHS_s[i] = rv;
    if (i == 0) RD_s[0] = rsqrtf(diag);
  }

  // --- factorization: 72 rank-8 supersteps
  for (int j = 0; j < NUM; j += 8) {
    __syncthreads();
    // ---- scale phase: wave 0, in-register 8-col micro-Cholesky (readlane)
    if (tid < 64) {
      const int t = tid;
      const int row = j + t;
      const bool rok = row < NUM;
      float v[8];
#pragma unroll
      for (int c = 0; c < 8; ++c) {
        const bool okc = rok && (t >= c) && (t - c <= 48);
        const int addr = okc ? (row * BSTR + (t - c)) : (NUM * BSTR + t);
        float vv = S[addr];
        v[c] = okc ? vv : 0.f;
      }
      float zb[8];
#pragma unroll
      for (int k = 0; k < 8; ++k) zb[k] = RHS_s[j + k];
      float z = RHS_s[rok ? row : j];
      z = rok ? z : 0.f;
      const float rd0 = RD_s[j];
      float rdv[8], y[8], lp[8][8];
#pragma unroll
      for (int k = 0; k < 8; ++k) {
        if (k == 0) {
          rdv[0] = rd0;
        } else {
          const float dk = rdlane(v[k], k);
          rdv[k] = rsqrtf(dk);
        }
        v[k] *= rdv[k];
#pragma unroll
        for (int m = k + 1; m < 8; ++m) {
          lp[m][k] = rdlane(v[k], m);
          v[m] -= v[k] * lp[m][k];
        }
      }
      // fused forward substitution (uniform scalars)
      y[0] = zb[0] * rdv[0];
#pragma unroll
      for (int k = 1; k < 8; ++k) {
        float a = zb[k];
#pragma unroll
        for (int m = 0; m < 8; ++m)
          if (m < k) a -= lp[k][m] * y[m];
        y[k] = a * rdv[k];
      }
      float zn = z;
#pragma unroll
      for (int c = 0; c < 8; ++c) zn -= v[c] * y[c];
      // stores: scaled columns to band + CP panel
#pragma unroll
      for (int c = 0; c < 8; ++c) {
        const bool okc = rok && (t > c) && (t - c <= 48);
        float* bp = okc ? &S[row * BSTR + (t - c)] : &S[NUM * BSTR + t];
        *bp = v[c];
        CP[c][t] = okc ? v[c] : 0.f;
      }
      if (t < 8) {
        float yv = y[0], rv = rdv[0];
#pragma unroll
        for (int k = 1; k < 8; ++k) {
          yv = (t == k) ? y[k] : yv;
          rv = (t == k) ? rdv[k] : rv;
        }
        RHS_s[row] = yv;
        RD_s[row] = rv;
      } else {
        float* rp = rok ? &RHS_s[row] : &DUMW[t & 63];
        *rp = zn;
      }
    }
    __syncthreads();
    // ---- rank-8 trailing update: one 2x2 tile per thread (8 waves)
    const int R = (NUM - 1) - j;
    {
      const bool a0 = (r1A <= R);
      const bool a1 = (r1A + 1 <= R);
      float2 cr[8], cc[8];
#pragma unroll
      for (int c = 0; c < 8; ++c) {
        cr[c] = *(const float2*)&CP[c][r1A & 62];
        cc[c] = *(const float2*)&CP[c][r2A];
      }
      float s00 = 0.f, s01 = 0.f, s10 = 0.f, s11 = 0.f;
#pragma unroll
      for (int c = 0; c < 8; ++c) {
        s00 += cr[c].x * cc[c].x; s01 += cr[c].x * cc[c].y;
        s10 += cr[c].y * cc[c].x; s11 += cr[c].y * cc[c].y;
      }
      const int p00 = j * BSTR + 51 * r1A - r2A;
      float* q00 = a0 ? &S[p00] : &S[NUM * BSTR + tid];
      float* q01 = a0 ? &S[p00 - 1] : &S[NUM * BSTR + tid];
      float* q10 = a1 ? &S[p00 + 51] : &S[NUM * BSTR + tid];
      float* q11 = a1 ? &S[p00 + 50] : &S[NUM * BSTR + tid];
      const float t00 = *q00 - s00, t01 = *q01 - s01;
      const float t10 = *q10 - s10, t11 = *q11 - s11;
      *q00 = t00; *q01 = t01; *q10 = t10; *q11 = t11;
      if (tid == 0 && a0)                  // tile (8,8): d_{j+8} final
        RD_s[j + 8] = rsqrtf(t00);
    }
  }
  __syncthreads();

  // --- back substitution: 72 rank-8 supersteps, single wave
  if (tid < 64) {
    const int t = tid;
    for (int i = NUM - 1; i >= 7; i -= 8) {
      asm volatile("s_waitcnt lgkmcnt(0)" ::: "memory");
      float zz[8], rr[8];
#pragma unroll
      for (int k = 0; k < 8; ++k) { zz[k] = RHS_s[i - k]; rr[k] = RD_s[i - k]; }
      float L[8][8];
#pragma unroll
      for (int a = 0; a < 8; ++a)
#pragma unroll
        for (int bb = 0; bb < 8; ++bb)
          if (bb > a) L[a][bb] = S[(i - a) * BSTR + (bb - a)];
      float x[8];
      x[0] = zz[0] * rr[0];
#pragma unroll
      for (int k = 1; k < 8; ++k) {
        float a = zz[k];
#pragma unroll
        for (int m = 0; m < 8; ++m)
          if (m < k) a -= L[m][k] * x[m];
        x[k] = a * rr[k];
      }
      const int rb = i - 8 - t;
      const bool bok = rb >= 0;
      float acc2 = 0.f;
#pragma unroll
      for (int k = 0; k < 8; ++k) {
        const int d = 8 + t - k;
        const bool ok = bok && (d <= 48);
        float Lv = S[ok ? ((i - k) * BSTR + d) : (NUM * BSTR + t)];
        Lv = ok ? Lv : 0.f;
        acc2 += Lv * x[k];
      }
      const float zbv = RHS_s[bok ? rb : 0];
      float* rp = bok ? &RHS_s[rb] : &DUMW[t];
      *rp = zbv - acc2;
      float xv = x[0];
#pragma unroll
      for (int k = 1; k < 8; ++k) xv = (t == k) ? x[k] : xv;
      if (t < 8) XS_s[i - t] = xv;
    }
  }
  __syncthreads();

  // --- write solution + accumulate GroupNorm stats (double)
  double ls = 0.0, ls2 = 0.0;
  for (int i = tid; i < NUM; i += CTH) {
    const float xv = XS_s[i];
    sol[(size_t)b * NUM + i] = xv;
    ls += (double)xv;
    ls2 += (double)xv * (double)xv;
  }
#pragma unroll
  for (int off = 32; off > 0; off >>= 1) {
    ls += __shfl_down(ls, off);
    ls2 += __shfl_down(ls2, off);
  }
  if ((tid & 63) == 0) {
    RW[(tid >> 6) * 2] = ls;
    RW[(tid >> 6) * 2 + 1] = ls2;
  }
  __syncthreads();
  if (tid == 0) {
    double s = 0.0, s2 = 0.0;
#pragma unroll
    for (int wv = 0; wv < 8; ++wv) { s += RW[wv * 2]; s2 += RW[wv * 2 + 1]; }
    atomicAdd(&acc[n * 2], s);
    atomicAdd(&acc[n * 2 + 1], s2);
  }
}

// ---------------------------------------------------------------------------
// post conv fused with GroupNorm-apply + SE scale.
// ---------------------------------------------------------------------------
__global__ __launch_bounds__(576) void postgn_kernel(
    const float* __restrict__ sol, const double* __restrict__ acc,
    const float* __restrict__ sev,
    const float* __restrict__ gnw, const float* __restrict__ gnb,
    const float* __restrict__ w, const float* __restrict__ bias,
    float* __restrict__ out)
{
  __shared__ float sy[16 * 576];
  const int co = blockIdx.x, n = blockIdx.y, tid = threadIdx.x;
  const double mu_d = acc[n * 2] * (1.0 / 9216.0);
  const double var_d = acc[n * 2 + 1] * (1.0 / 9216.0) - mu_d * mu_d;
  const float rstd = (float)(1.0 / sqrt(var_d + 1e-5));
  const float muf = (float)mu_d;
  {
    const float4* sp4 = (const float4*)(sol + (size_t)n * 9216);
    float4* sy4 = (float4*)sy;
#pragma unroll
    for (int q = 0; q < 4; ++q) {
      const int p = tid + q * 576;
      const int k = p / 144;
      const float sv = sev[n * 16 + k];
      const float A = rstd * gnw[k] * sv;
      const float B = (gnb[k] - muf * rstd * gnw[k]) * sv;
      float4 v = sp4[p];
      v.x = v.x * A + B; v.y = v.y * A + B;
      v.z = v.z * A + B; v.w = v.w * A + B;
      sy4[p] = v;
    }
  }
  __syncthreads();
  const int py = tid / 24, px = tid - py * 24;
  float a = bias[co];
#pragma unroll 4
  for (int k = 0; k < 16; ++k) {
    const float* wp = w + (co * 16 + k) * 9;
#pragma unroll
    for (int dy = 0; dy < 3; ++dy) {
      const int yy = py + dy - 1;
      const bool oky = (unsigned)yy < 24u;
      const int iy = yy < 0 ? 0 : (yy > 23 ? 23 : yy);
#pragma unroll
      for (int dx = 0; dx < 3; ++dx) {
        const int xx = px + dx - 1;
        const bool ok = oky && ((unsigned)xx < 24u);
        const int ix = xx < 0 ? 0 : (xx > 23 ? 23 : xx);
        const float v = ok ? sy[k * 576 + iy * 24 + ix] : 0.f;
        a += v * wp[dy * 3 + dx];
      }
    }
  }
  out[(size_t)(n * 128 + co) * 576 + tid] = a;
}

// ---------------------------------------------------------------------------
extern "C" void kernel_launch(void* const* d_in, const int* in_sizes, int n_in,
                              void* d_out, int out_size, void* d_ws, size_t ws_size,
                              hipStream_t stream) {
  const float* x       = (const float*)d_in[0];
  const float* grad_w1 = (const float*)d_in[2];
  const float* grad_b1 = (const float*)d_in[3];
  const float* grad_w2 = (const float*)d_in[4];
  const float* grad_b2 = (const float*)d_in[5];
  const float* att_w1  = (const float*)d_in[6];
  const float* att_b1  = (const float*)d_in[7];
  const float* att_w2  = (const float*)d_in[8];
  const float* att_b2  = (const float*)d_in[9];
  const float* se_w1   = (const float*)d_in[10];
  const float* se_b1   = (const float*)d_in[11];
  const float* se_w2   = (const float*)d_in[12];
  const float* se_b2   = (const float*)d_in[13];
  const float* gn_w    = (const float*)d_in[14];
  const float* gn_b    = (const float*)d_in[15];
  const float* post_w  = (const float*)d_in[16];
  const float* post_b  = (const float*)d_in[17];
  float* out = (float*)d_out;

  float* ws  = (float*)d_ws;
  float* t1a = ws;              // 147456
  float* t1g = t1a + 147456;    // 147456
  float* att = t1g + 147456;    // 147456
  float* grd = att + 147456;    // 147456
  float* sev = grd + 147456;    // 64
  float* sol = sev + 64;        // 36864
  double* acc = (double*)(sol + 36864);  // 8 doubles

  (void)hipFuncSetAttribute((const void*)chol_kernel,
                            hipFuncAttributeMaxDynamicSharedMemorySize,
                            (int)CHOL_LDS_BYTES);

  conv1se_kernel<<<dim3(65, 4), 576, 0, stream>>>(
      x, att_w1, att_b1, grad_w1, grad_b1,
      se_w1, se_b1, se_w2, se_b2, t1a, t1g, sev, acc);
  conv2_kernel<<<dim3(64, 4, 2), 576, 0, stream>>>(t1a, t1g, att_w2, att_b2,
                                                   grad_w2, grad_b2, att, grd);
  chol_kernel<<<64, CTH, CHOL_LDS_BYTES, stream>>>(att, grd, sol, acc);
  postgn_kernel<<<dim3(128, 4), 576, 0, stream>>>(sol, acc, sev, gn_w, gn_b,
                                                  post_w, post_b, out);
}